// Round 15
// baseline (654.390 us; speedup 1.0000x reference)
//
#include <hip/hip_runtime.h>
#include <math.h>

#define BB 48
#define TT 32
#define DD 1024
#define SZ 512
#define NCELLS 528  // 32*33/2

typedef unsigned short u16;
typedef unsigned int u32;
typedef __attribute__((ext_vector_type(8))) short bf16x8;
typedef __attribute__((ext_vector_type(4))) float f32x4;
typedef __attribute__((ext_vector_type(2))) float f32x2;

__device__ __forceinline__ int off_of(int k) { return TT * k - (k * (k - 1)) / 2; }

__device__ __forceinline__ u16 f2bf(float x) {
    u32 u = __float_as_uint(x);
    u32 r = (u + 0x7fffu + ((u >> 16) & 1u)) >> 16;
    return (u16)r;
}
__device__ __forceinline__ float bf2f(u16 h) {
    return __uint_as_float(((u32)h) << 16);
}
__device__ __forceinline__ u32 pack2(u16 a, u16 b) {
    return (u32)a | ((u32)b << 16);
}
__device__ __forceinline__ float2 upk(u32 v) {
    return make_float2(__uint_as_float(v << 16),
                       __uint_as_float(v & 0xffff0000u));
}

// ---------------------------------------------------------------------------
// prep_all: both weight preps in one launch.
// ---------------------------------------------------------------------------
__global__ __launch_bounds__(256) void prep_all(
    const float* __restrict__ w_comp, const float* __restrict__ s_bil,
    const float* __restrict__ w_leaf,
    u16* __restrict__ WT, u16* __restrict__ WLT_hi, u16* __restrict__ WLT_lo)
{
    int idx = blockIdx.x * 256 + threadIdx.x;
    if (idx < 1536 * 512) {
        int n = idx >> 9, k = idx & 511;
        float w;
        if (n < 512)       w = w_comp[(size_t)k * SZ + n];
        else if (n < 1024) w = w_comp[(size_t)(512 + k) * SZ + (n - 512)];
        else               w = s_bil[(size_t)k * SZ + (n - 1024)];
        WT[idx] = f2bf(w);
    } else {
        int i = idx - 1536 * 512;          // n*1024 + k
        int n = i >> 10, k = i & 1023;
        float w = w_leaf[(size_t)k * SZ + n];
        u16 hi = f2bf(w);
        u16 lo = f2bf(w - bf2f(hi));
        WLT_hi[i] = hi;
        WLT_lo[i] = lo;
    }
}

// ---------------------------------------------------------------------------
// leaf_mfma: leaf_pre = relu(x @ w_leaf + b_leaf). x plain bf16; W hi/lo.
// Tile 128x64, 4 waves (2x2), wave 64x32, K=1024, BK=32. grid (8, 12).
// ---------------------------------------------------------------------------
__global__ __launch_bounds__(256) void leaf_mfma(
    const float* __restrict__ x,
    const u16* __restrict__ WLT_hi, const u16* __restrict__ WLT_lo,
    const float* __restrict__ b_leaf, float* __restrict__ leaf_pre)
{
    __shared__ u16 Ah[128][40];
    __shared__ u16 Bh[64][40], Bl[64][40];

    const int col0 = blockIdx.x * 64;
    const int row0 = blockIdx.y * 128;
    const int t = threadIdx.x;

    const int srow = t >> 1, skh = (t & 1) * 16;
    const float* ap = x + (size_t)(row0 + srow) * DD + skh;
    const int bcol = t >> 2, bch = (t & 3) * 8;
    const u16* bph = WLT_hi + (size_t)(col0 + bcol) * DD + bch;
    const u16* bpl = WLT_lo + (size_t)(col0 + bcol) * DD + bch;

    const int lane = t & 63, wv = t >> 6;
    const int wr = wv >> 1, wc = wv & 1;
    const int l15 = lane & 15, lko = (lane >> 4) * 8;

    f32x4 acc[4][2];
    #pragma unroll
    for (int i = 0; i < 4; ++i)
        #pragma unroll
        for (int j = 0; j < 2; ++j)
            #pragma unroll
            for (int e = 0; e < 4; ++e) acc[i][j][e] = 0.f;

    float4 pa[4];
    uint4 pbh, pbl;
    #pragma unroll
    for (int c = 0; c < 4; ++c) pa[c] = *(const float4*)(ap + c * 4);
    pbh = *(const uint4*)bph;
    pbl = *(const uint4*)bpl;

    for (int k0 = 0; k0 < DD; k0 += 32) {
        u32 wh[8];
        #pragma unroll
        for (int c = 0; c < 4; ++c) {
            wh[c * 2]     = pack2(f2bf(pa[c].x), f2bf(pa[c].y));
            wh[c * 2 + 1] = pack2(f2bf(pa[c].z), f2bf(pa[c].w));
        }
        *(uint4*)&Ah[srow][skh]     = make_uint4(wh[0], wh[1], wh[2], wh[3]);
        *(uint4*)&Ah[srow][skh + 8] = make_uint4(wh[4], wh[5], wh[6], wh[7]);
        *(uint4*)&Bh[bcol][bch] = pbh;
        *(uint4*)&Bl[bcol][bch] = pbl;
        __syncthreads();

        if (k0 + 32 < DD) {
            #pragma unroll
            for (int c = 0; c < 4; ++c)
                pa[c] = *(const float4*)(ap + k0 + 32 + c * 4);
            pbh = *(const uint4*)(bph + k0 + 32);
            pbl = *(const uint4*)(bpl + k0 + 32);
        }

        bf16x8 fah[4], fbh[2], fbl[2];
        #pragma unroll
        for (int i = 0; i < 4; ++i)
            fah[i] = *(const bf16x8*)&Ah[wr * 64 + i * 16 + l15][lko];
        #pragma unroll
        for (int j = 0; j < 2; ++j) {
            fbh[j] = *(const bf16x8*)&Bh[wc * 32 + j * 16 + l15][lko];
            fbl[j] = *(const bf16x8*)&Bl[wc * 32 + j * 16 + l15][lko];
        }
        #pragma unroll
        for (int i = 0; i < 4; ++i) {
            #pragma unroll
            for (int j = 0; j < 2; ++j) {
                acc[i][j] = __builtin_amdgcn_mfma_f32_16x16x32_bf16(
                    fah[i], fbh[j], acc[i][j], 0, 0, 0);
                acc[i][j] = __builtin_amdgcn_mfma_f32_16x16x32_bf16(
                    fah[i], fbl[j], acc[i][j], 0, 0, 0);
            }
        }
        __syncthreads();
    }

    #pragma unroll
    for (int i = 0; i < 4; ++i) {
        int rbase = row0 + wr * 64 + i * 16 + (lane >> 4) * 4;
        #pragma unroll
        for (int j = 0; j < 2; ++j) {
            int gc = col0 + wc * 32 + j * 16 + l15;
            float bc = b_leaf[gc];
            #pragma unroll
            for (int q = 0; q < 4; ++q)
                leaf_pre[(size_t)(rbase + q) * SZ + gc] =
                    fmaxf(acc[i][j][q] + bc, 0.f);
        }
    }
}

// leaf_norm: normalize rows, write chart_h f32 (NT) + Hchart bf16 + Sarr=0.
__global__ __launch_bounds__(256) void leaf_norm(
    const float* __restrict__ leaf_pre, float* __restrict__ chart_h,
    u16* __restrict__ Hchart, float* __restrict__ Sarr)
{
    const int r = blockIdx.x;               // 0..1535 = b*32+pos
    const int b = r >> 5, pos = r & 31;
    const int cell = b * NCELLS + pos;
    const int t = threadIdx.x, lane = t & 63, wave = t >> 6;
    __shared__ float red[4];

    float2 v = *(const float2*)&leaf_pre[(size_t)r * SZ + 2 * t];
    float sq = v.x * v.x + v.y * v.y;
    #pragma unroll
    for (int o = 32; o; o >>= 1) sq += __shfl_xor(sq, o);
    if (lane == 0) red[wave] = sq;
    __syncthreads();
    float nrm = sqrtf(red[0] + red[1] + red[2] + red[3]);
    float inv = 1.f / fmaxf(nrm, 1e-12f);
    v.x *= inv; v.y *= inv;
    f32x2 vv; vv.x = v.x; vv.y = v.y;
    __builtin_nontemporal_store(vv, (f32x2*)&chart_h[(size_t)cell * SZ + 2 * t]);
    ((u32*)Hchart)[(size_t)cell * 256 + t] = pack2(f2bf(v.x), f2bf(v.y));
    if (t == 0) Sarr[cell] = 0.f;
}

// ---------------------------------------------------------------------------
// transform_mfma: ACU[cell][0:1536] (bf16) = h[cell] @ Wcat [+ b_comp on A].
// 64x64 tile, 4 waves (2x2), wave 32x32, BK=32. ROW-chunk XCD pinning.
// ---------------------------------------------------------------------------
__global__ __launch_bounds__(256) void transform_mfma(
    const u16* __restrict__ Hchart, const u16* __restrict__ WT,
    const float* __restrict__ b_comp,
    u16* __restrict__ ACU, int level, int nrt)
{
    __shared__ u16 Ah[64][40];
    __shared__ u16 Bh[64][40];
    __shared__ int cidx[64];

    const int L = TT - level, rows = BB * L, off = off_of(level);
    const int id = blockIdx.x;
    const int w = (id & 7) * (3 * nrt) + (id >> 3);   // T/8 = 3*nrt
    const int rt = w / 24, ct = w % 24;
    const int col0 = ct * 64;

    const int t = threadIdx.x;
    if (t < 64) {
        int g = rt * 64 + t;
        cidx[t] = (g < rows) ? ((g / L) * NCELLS + off + (g % L)) : -1;
    }

    const int srow = t >> 2, skc = (t & 3) * 8;
    int ga = rt * 64 + srow;
    if (ga >= rows) ga = rows - 1;          // clamp: safe read, store guarded
    const int acell = (ga / L) * NCELLS + off + (ga % L);
    const u16* aph = Hchart + (size_t)acell * SZ + skc;
    const u16* bph = WT + (size_t)(col0 + srow) * SZ + skc;

    const int lane = t & 63, wv = t >> 6;
    const int wr = wv >> 1, wc = wv & 1;
    const int l15 = lane & 15, lko = (lane >> 4) * 8;

    f32x4 acc[2][2];
    #pragma unroll
    for (int i = 0; i < 2; ++i)
        #pragma unroll
        for (int j = 0; j < 2; ++j)
            #pragma unroll
            for (int e = 0; e < 4; ++e) acc[i][j][e] = 0.f;

    uint4 pah = *(const uint4*)aph;
    uint4 pbh = *(const uint4*)bph;

    for (int k0 = 0; k0 < SZ; k0 += 32) {
        *(uint4*)&Ah[srow][skc] = pah;
        *(uint4*)&Bh[srow][skc] = pbh;
        __syncthreads();

        if (k0 + 32 < SZ) {
            pah = *(const uint4*)(aph + k0 + 32);
            pbh = *(const uint4*)(bph + k0 + 32);
        }

        bf16x8 fah[2], fbh[2];
        #pragma unroll
        for (int i = 0; i < 2; ++i)
            fah[i] = *(const bf16x8*)&Ah[wr * 32 + i * 16 + l15][lko];
        #pragma unroll
        for (int j = 0; j < 2; ++j)
            fbh[j] = *(const bf16x8*)&Bh[wc * 32 + j * 16 + l15][lko];
        #pragma unroll
        for (int i = 0; i < 2; ++i)
            #pragma unroll
            for (int j = 0; j < 2; ++j)
                acc[i][j] = __builtin_amdgcn_mfma_f32_16x16x32_bf16(
                    fah[i], fbh[j], acc[i][j], 0, 0, 0);
        __syncthreads();
    }

    #pragma unroll
    for (int i = 0; i < 2; ++i) {
        int rbase = wr * 32 + i * 16 + (lane >> 4) * 4;
        #pragma unroll
        for (int j = 0; j < 2; ++j) {
            int gc = col0 + wc * 32 + j * 16 + l15;
            float bias = (gc < 512) ? b_comp[gc] : 0.f;  // fold comp bias into A
            #pragma unroll
            for (int q = 0; q < 4; ++q) {
                int ci = cidx[rbase + q];
                if (ci >= 0)
                    ACU[(size_t)ci * 1536 + gc] = f2bf(acc[i][j][q] + bias);
            }
        }
    }
}

// ---------------------------------------------------------------------------
// Combine: 512 threads (8 waves); XCD-swizzled; fully-unrolled 4-slot n-pass
// (slots wv, wv+8, wv+16, wv+24 cover all N <= 31 -> 8 loads in flight).
// bf16 ACU/Hchart reads; NT f32 chart writes. A carries the comp bias.
// ---------------------------------------------------------------------------
__global__ __launch_bounds__(512) void combine_kernel(
    float* __restrict__ chart_h, const u16* __restrict__ ACU,
    const u16* __restrict__ Hchart,
    float* __restrict__ Sarr, u16* __restrict__ Hchart_w, int level)
{
    const int L = TT - level, N = level;
    // XCD swizzle: grid C = 48L divisible by 8; XCD x gets b in [6x, 6x+6)
    const int cpx = (BB * L) >> 3;
    const int swz = (blockIdx.x & 7) * cpx + (blockIdx.x >> 3);
    const int b = swz / L, pos = swz % L;
    const int off = off_of(level);

    __shared__ float s_lds[32], p_lds[32], spre[32];
    __shared__ int lcell[32], rcell[32];
    __shared__ float hred[8][512];
    __shared__ float red[8];

    const int t = threadIdx.x, lane = t & 63, wv = t >> 6;

    if (t < N) {
        int lc = b * NCELLS + off_of(t) + pos;
        int rc = b * NCELLS + off_of(level - t - 1) + pos + t + 1;
        lcell[t] = lc;
        rcell[t] = rc;
        spre[t] = Sarr[lc] + Sarr[rc];
    }
    __syncthreads();

    const int n0 = wv, n1 = wv + 8, n2 = wv + 16, n3 = wv + 24;
    const bool v0 = n0 < N, v1 = n1 < N, v2 = n2 < N, v3 = n3 < N;
    const int j0 = v0 ? n0 : 0;
    const int j1 = v1 ? n1 : 0;
    const int j2 = v2 ? n2 : 0;
    const int j3 = v3 ? n3 : 0;

    // phase 1: s_n = u_l . h_r + s_l + s_r  (4 slots, 8 loads in flight)
    {
        const u16* u0  = ACU + (size_t)lcell[j0] * 1536 + 1024;
        const u16* u1  = ACU + (size_t)lcell[j1] * 1536 + 1024;
        const u16* u2  = ACU + (size_t)lcell[j2] * 1536 + 1024;
        const u16* u3  = ACU + (size_t)lcell[j3] * 1536 + 1024;
        const u16* h0  = Hchart + (size_t)rcell[j0] * SZ;
        const u16* h1  = Hchart + (size_t)rcell[j1] * SZ;
        const u16* h2  = Hchart + (size_t)rcell[j2] * SZ;
        const u16* h3  = Hchart + (size_t)rcell[j3] * SZ;
        uint4 uva = *(const uint4*)&u0[lane * 8];
        uint4 hva = *(const uint4*)&h0[lane * 8];
        uint4 uvb = *(const uint4*)&u1[lane * 8];
        uint4 hvb = *(const uint4*)&h1[lane * 8];
        uint4 uvc = *(const uint4*)&u2[lane * 8];
        uint4 hvc = *(const uint4*)&h2[lane * 8];
        uint4 uvd = *(const uint4*)&u3[lane * 8];
        uint4 hvd = *(const uint4*)&h3[lane * 8];
        const u32 ua[4] = {uva.x, uva.y, uva.z, uva.w};
        const u32 ha[4] = {hva.x, hva.y, hva.z, hva.w};
        const u32 ub[4] = {uvb.x, uvb.y, uvb.z, uvb.w};
        const u32 hb[4] = {hvb.x, hvb.y, hvb.z, hvb.w};
        const u32 uc[4] = {uvc.x, uvc.y, uvc.z, uvc.w};
        const u32 hc[4] = {hvc.x, hvc.y, hvc.z, hvc.w};
        const u32 ud[4] = {uvd.x, uvd.y, uvd.z, uvd.w};
        const u32 hd[4] = {hvd.x, hvd.y, hvd.z, hvd.w};
        float d0 = 0.f, d1 = 0.f, d2 = 0.f, d3 = 0.f;
        #pragma unroll
        for (int c = 0; c < 4; ++c) {
            float2 a0 = upk(ua[c]), g0 = upk(ha[c]);
            float2 a1 = upk(ub[c]), g1 = upk(hb[c]);
            float2 a2 = upk(uc[c]), g2 = upk(hc[c]);
            float2 a3 = upk(ud[c]), g3 = upk(hd[c]);
            d0 = fmaf(a0.x, g0.x, fmaf(a0.y, g0.y, d0));
            d1 = fmaf(a1.x, g1.x, fmaf(a1.y, g1.y, d1));
            d2 = fmaf(a2.x, g2.x, fmaf(a2.y, g2.y, d2));
            d3 = fmaf(a3.x, g3.x, fmaf(a3.y, g3.y, d3));
        }
        #pragma unroll
        for (int o = 32; o; o >>= 1) {
            d0 += __shfl_xor(d0, o);
            d1 += __shfl_xor(d1, o);
            d2 += __shfl_xor(d2, o);
            d3 += __shfl_xor(d3, o);
        }
        if (lane == 0) {
            if (v0) s_lds[n0] = d0 + spre[n0];
            if (v1) s_lds[n1] = d1 + spre[n1];
            if (v2) s_lds[n2] = d2 + spre[n2];
            if (v3) s_lds[n3] = d3 + spre[n3];
        }
    }
    __syncthreads();

    // phase 1b: softmax + sbar (wave 0)
    if (wv == 0) {
        float sv = (lane < N) ? s_lds[lane] : -INFINITY;
        float m = sv;
        #pragma unroll
        for (int o = 32; o; o >>= 1) m = fmaxf(m, __shfl_xor(m, o));
        float e = (lane < N) ? expf(sv - m) : 0.f;
        float sum = e;
        #pragma unroll
        for (int o = 32; o; o >>= 1) sum += __shfl_xor(sum, o);
        float p = e / sum;
        if (lane < N) p_lds[lane] = p;
        float sb = (lane < N) ? sv * p : 0.f;
        #pragma unroll
        for (int o = 32; o; o >>= 1) sb += __shfl_xor(sb, o);
        if (lane == 0) Sarr[(size_t)b * NCELLS + off + pos] = sb;
    }
    __syncthreads();

    // phase 2: per-wave partial hbar (4 slots, 8 loads in flight)
    float hacc[8];
    #pragma unroll
    for (int q = 0; q < 8; ++q) hacc[q] = 0.f;
    {
        const u16* A0 = ACU + (size_t)lcell[j0] * 1536;
        const u16* C0 = ACU + (size_t)rcell[j0] * 1536 + 512;
        const u16* A1 = ACU + (size_t)lcell[j1] * 1536;
        const u16* C1 = ACU + (size_t)rcell[j1] * 1536 + 512;
        const u16* A2 = ACU + (size_t)lcell[j2] * 1536;
        const u16* C2 = ACU + (size_t)rcell[j2] * 1536 + 512;
        const u16* A3 = ACU + (size_t)lcell[j3] * 1536;
        const u16* C3 = ACU + (size_t)rcell[j3] * 1536 + 512;
        uint4 va0 = *(const uint4*)&A0[lane * 8];
        uint4 vc0 = *(const uint4*)&C0[lane * 8];
        uint4 va1 = *(const uint4*)&A1[lane * 8];
        uint4 vc1 = *(const uint4*)&C1[lane * 8];
        uint4 va2 = *(const uint4*)&A2[lane * 8];
        uint4 vc2 = *(const uint4*)&C2[lane * 8];
        uint4 va3 = *(const uint4*)&A3[lane * 8];
        uint4 vc3 = *(const uint4*)&C3[lane * 8];
        float p0 = v0 ? p_lds[n0] : 0.f;
        float p1 = v1 ? p_lds[n1] : 0.f;
        float p2 = v2 ? p_lds[n2] : 0.f;
        float p3 = v3 ? p_lds[n3] : 0.f;
        const u32 aa[4] = {va0.x, va0.y, va0.z, va0.w};
        const u32 ca[4] = {vc0.x, vc0.y, vc0.z, vc0.w};
        const u32 ab[4] = {va1.x, va1.y, va1.z, va1.w};
        const u32 cb[4] = {vc1.x, vc1.y, vc1.z, vc1.w};
        const u32 ac[4] = {va2.x, va2.y, va2.z, va2.w};
        const u32 cc[4] = {vc2.x, vc2.y, vc2.z, vc2.w};
        const u32 ad[4] = {va3.x, va3.y, va3.z, va3.w};
        const u32 cd[4] = {vc3.x, vc3.y, vc3.z, vc3.w};
        #pragma unroll
        for (int c = 0; c < 4; ++c) {
            float2 x0 = upk(aa[c]), y0 = upk(ca[c]);
            float2 x1 = upk(ab[c]), y1 = upk(cb[c]);
            float2 x2 = upk(ac[c]), y2 = upk(cc[c]);
            float2 x3 = upk(ad[c]), y3 = upk(cd[c]);
            hacc[c * 2]     = fmaf(p0, fmaxf(x0.x + y0.x, 0.f), hacc[c * 2]);
            hacc[c * 2 + 1] = fmaf(p0, fmaxf(x0.y + y0.y, 0.f), hacc[c * 2 + 1]);
            hacc[c * 2]     = fmaf(p1, fmaxf(x1.x + y1.x, 0.f), hacc[c * 2]);
            hacc[c * 2 + 1] = fmaf(p1, fmaxf(x1.y + y1.y, 0.f), hacc[c * 2 + 1]);
            hacc[c * 2]     = fmaf(p2, fmaxf(x2.x + y2.x, 0.f), hacc[c * 2]);
            hacc[c * 2 + 1] = fmaf(p2, fmaxf(x2.y + y2.y, 0.f), hacc[c * 2 + 1]);
            hacc[c * 2]     = fmaf(p3, fmaxf(x3.x + y3.x, 0.f), hacc[c * 2]);
            hacc[c * 2 + 1] = fmaf(p3, fmaxf(x3.y + y3.y, 0.f), hacc[c * 2 + 1]);
        }
    }
    *(float4*)&hred[wv][lane * 8]     = *(float4*)&hacc[0];
    *(float4*)&hred[wv][lane * 8 + 4] = *(float4*)&hacc[4];
    __syncthreads();

    // final: thread t owns output t (512 threads)
    float hv = hred[0][t] + hred[1][t] + hred[2][t] + hred[3][t]
             + hred[4][t] + hred[5][t] + hred[6][t] + hred[7][t];

    float sq = hv * hv;
    #pragma unroll
    for (int o = 32; o; o >>= 1) sq += __shfl_xor(sq, o);
    if (lane == 0) red[wv] = sq;
    __syncthreads();
    float nrm = sqrtf(((red[0] + red[1]) + (red[2] + red[3]))
                    + ((red[4] + red[5]) + (red[6] + red[7])));
    float inv = 1.f / fmaxf(nrm, 1e-12f);
    hv *= inv;
    hred[0][t] = hv;
    __syncthreads();
    const int ocell = b * NCELLS + off + pos;
    if (t < 256) {
        float x0 = hred[0][2 * t], x1 = hred[0][2 * t + 1];
        f32x2 vv; vv.x = x0; vv.y = x1;
        __builtin_nontemporal_store(vv,
            (f32x2*)&chart_h[(size_t)ocell * SZ + 2 * t]);
        ((u32*)Hchart_w)[(size_t)ocell * 256 + t] = pack2(f2bf(x0), f2bf(x1));
    }
}

// ---------------------------------------------------------------------------
extern "C" void kernel_launch(void* const* d_in, const int* in_sizes, int n_in,
                              void* d_out, int out_size, void* d_ws, size_t ws_size,
                              hipStream_t stream)
{
    const float* x      = (const float*)d_in[0];
    const float* w_leaf = (const float*)d_in[1];
    const float* b_leaf = (const float*)d_in[2];
    const float* w_comp = (const float*)d_in[3];
    const float* b_comp = (const float*)d_in[4];
    const float* s_bil  = (const float*)d_in[5];
    float* chart_h = (float*)d_out;

    char* ws = (char*)d_ws;
    u16* ACU    = (u16*)ws;                        ws += (size_t)BB * NCELLS * 1536 * 2;
    u16* Hchart = (u16*)ws;                        ws += (size_t)BB * NCELLS * SZ * 2;
    float* Sarr = (float*)ws;                      ws += (size_t)BB * NCELLS * 4;
    u16* WT     = (u16*)ws;                        ws += (size_t)1536 * SZ * 2;
    u16* WLT_hi = (u16*)ws;                        ws += (size_t)SZ * DD * 2;
    u16* WLT_lo = (u16*)ws;                        ws += (size_t)SZ * DD * 2;
    float* leaf_pre = (float*)ws;                  ws += (size_t)BB * TT * SZ * 4;

    prep_all<<<(1536 * 512 + 512 * 1024) / 256, 256, 0, stream>>>(
        w_comp, s_bil, w_leaf, WT, WLT_hi, WLT_lo);
    leaf_mfma<<<dim3(8, 12), 256, 0, stream>>>(x, WLT_hi, WLT_lo, b_leaf, leaf_pre);
    leaf_norm<<<BB * TT, 256, 0, stream>>>(leaf_pre, chart_h, Hchart, Sarr);

    {
        int nrt = (BB * TT + 63) / 64;   // 24
        transform_mfma<<<24 * nrt, 256, 0, stream>>>(
            Hchart, WT, b_comp, ACU, 0, nrt);
    }

    for (int level = 1; level < TT; ++level) {
        int L = TT - level;
        combine_kernel<<<BB * L, 512, 0, stream>>>(
            chart_h, ACU, Hchart, Sarr, Hchart, level);
        if (level < TT - 1) {
            int nrt = (BB * L + 63) / 64;
            transform_mfma<<<24 * nrt, 256, 0, stream>>>(
                Hchart, WT, b_comp, ACU, level, nrt);
        }
    }
}

// Round 16
// 628.804 us; speedup vs baseline: 1.0407x; 1.0407x over previous
//
#include <hip/hip_runtime.h>
#include <math.h>

#define BB 48
#define TT 32
#define DD 1024
#define SZ 512
#define NCELLS 528  // 32*33/2

typedef unsigned short u16;
typedef unsigned int u32;
typedef __attribute__((ext_vector_type(8))) short bf16x8;
typedef __attribute__((ext_vector_type(4))) float f32x4;
typedef __attribute__((ext_vector_type(2))) float f32x2;

__device__ __forceinline__ int off_of(int k) { return TT * k - (k * (k - 1)) / 2; }

__device__ __forceinline__ u16 f2bf(float x) {
    u32 u = __float_as_uint(x);
    u32 r = (u + 0x7fffu + ((u >> 16) & 1u)) >> 16;
    return (u16)r;
}
__device__ __forceinline__ float bf2f(u16 h) {
    return __uint_as_float(((u32)h) << 16);
}
__device__ __forceinline__ u32 pack2(u16 a, u16 b) {
    return (u32)a | ((u32)b << 16);
}
__device__ __forceinline__ float2 upk(u32 v) {
    return make_float2(__uint_as_float(v << 16),
                       __uint_as_float(v & 0xffff0000u));
}

// ---------------------------------------------------------------------------
// prep_all: both weight preps in one launch.
// ---------------------------------------------------------------------------
__global__ __launch_bounds__(256) void prep_all(
    const float* __restrict__ w_comp, const float* __restrict__ s_bil,
    const float* __restrict__ w_leaf,
    u16* __restrict__ WT, u16* __restrict__ WLT_hi, u16* __restrict__ WLT_lo)
{
    int idx = blockIdx.x * 256 + threadIdx.x;
    if (idx < 1536 * 512) {
        int n = idx >> 9, k = idx & 511;
        float w;
        if (n < 512)       w = w_comp[(size_t)k * SZ + n];
        else if (n < 1024) w = w_comp[(size_t)(512 + k) * SZ + (n - 512)];
        else               w = s_bil[(size_t)k * SZ + (n - 1024)];
        WT[idx] = f2bf(w);
    } else {
        int i = idx - 1536 * 512;          // n*1024 + k
        int n = i >> 10, k = i & 1023;
        float w = w_leaf[(size_t)k * SZ + n];
        u16 hi = f2bf(w);
        u16 lo = f2bf(w - bf2f(hi));
        WLT_hi[i] = hi;
        WLT_lo[i] = lo;
    }
}

// ---------------------------------------------------------------------------
// leaf_mfma: leaf_pre = relu(x @ w_leaf + b_leaf). x plain bf16; W hi/lo.
// Tile 128x64, 4 waves (2x2), wave 64x32, K=1024, BK=32. grid (8, 12).
// ---------------------------------------------------------------------------
__global__ __launch_bounds__(256) void leaf_mfma(
    const float* __restrict__ x,
    const u16* __restrict__ WLT_hi, const u16* __restrict__ WLT_lo,
    const float* __restrict__ b_leaf, float* __restrict__ leaf_pre)
{
    __shared__ u16 Ah[128][40];
    __shared__ u16 Bh[64][40], Bl[64][40];

    const int col0 = blockIdx.x * 64;
    const int row0 = blockIdx.y * 128;
    const int t = threadIdx.x;

    const int srow = t >> 1, skh = (t & 1) * 16;
    const float* ap = x + (size_t)(row0 + srow) * DD + skh;
    const int bcol = t >> 2, bch = (t & 3) * 8;
    const u16* bph = WLT_hi + (size_t)(col0 + bcol) * DD + bch;
    const u16* bpl = WLT_lo + (size_t)(col0 + bcol) * DD + bch;

    const int lane = t & 63, wv = t >> 6;
    const int wr = wv >> 1, wc = wv & 1;
    const int l15 = lane & 15, lko = (lane >> 4) * 8;

    f32x4 acc[4][2];
    #pragma unroll
    for (int i = 0; i < 4; ++i)
        #pragma unroll
        for (int j = 0; j < 2; ++j)
            #pragma unroll
            for (int e = 0; e < 4; ++e) acc[i][j][e] = 0.f;

    float4 pa[4];
    uint4 pbh, pbl;
    #pragma unroll
    for (int c = 0; c < 4; ++c) pa[c] = *(const float4*)(ap + c * 4);
    pbh = *(const uint4*)bph;
    pbl = *(const uint4*)bpl;

    for (int k0 = 0; k0 < DD; k0 += 32) {
        u32 wh[8];
        #pragma unroll
        for (int c = 0; c < 4; ++c) {
            wh[c * 2]     = pack2(f2bf(pa[c].x), f2bf(pa[c].y));
            wh[c * 2 + 1] = pack2(f2bf(pa[c].z), f2bf(pa[c].w));
        }
        *(uint4*)&Ah[srow][skh]     = make_uint4(wh[0], wh[1], wh[2], wh[3]);
        *(uint4*)&Ah[srow][skh + 8] = make_uint4(wh[4], wh[5], wh[6], wh[7]);
        *(uint4*)&Bh[bcol][bch] = pbh;
        *(uint4*)&Bl[bcol][bch] = pbl;
        __syncthreads();

        if (k0 + 32 < DD) {
            #pragma unroll
            for (int c = 0; c < 4; ++c)
                pa[c] = *(const float4*)(ap + k0 + 32 + c * 4);
            pbh = *(const uint4*)(bph + k0 + 32);
            pbl = *(const uint4*)(bpl + k0 + 32);
        }

        bf16x8 fah[4], fbh[2], fbl[2];
        #pragma unroll
        for (int i = 0; i < 4; ++i)
            fah[i] = *(const bf16x8*)&Ah[wr * 64 + i * 16 + l15][lko];
        #pragma unroll
        for (int j = 0; j < 2; ++j) {
            fbh[j] = *(const bf16x8*)&Bh[wc * 32 + j * 16 + l15][lko];
            fbl[j] = *(const bf16x8*)&Bl[wc * 32 + j * 16 + l15][lko];
        }
        #pragma unroll
        for (int i = 0; i < 4; ++i) {
            #pragma unroll
            for (int j = 0; j < 2; ++j) {
                acc[i][j] = __builtin_amdgcn_mfma_f32_16x16x32_bf16(
                    fah[i], fbh[j], acc[i][j], 0, 0, 0);
                acc[i][j] = __builtin_amdgcn_mfma_f32_16x16x32_bf16(
                    fah[i], fbl[j], acc[i][j], 0, 0, 0);
            }
        }
        __syncthreads();
    }

    #pragma unroll
    for (int i = 0; i < 4; ++i) {
        int rbase = row0 + wr * 64 + i * 16 + (lane >> 4) * 4;
        #pragma unroll
        for (int j = 0; j < 2; ++j) {
            int gc = col0 + wc * 32 + j * 16 + l15;
            float bc = b_leaf[gc];
            #pragma unroll
            for (int q = 0; q < 4; ++q)
                leaf_pre[(size_t)(rbase + q) * SZ + gc] =
                    fmaxf(acc[i][j][q] + bc, 0.f);
        }
    }
}

// leaf_norm: normalize rows, write chart_h f32 (NT) + Hchart bf16 + Sarr=0.
__global__ __launch_bounds__(256) void leaf_norm(
    const float* __restrict__ leaf_pre, float* __restrict__ chart_h,
    u16* __restrict__ Hchart, float* __restrict__ Sarr)
{
    const int r = blockIdx.x;               // 0..1535 = b*32+pos
    const int b = r >> 5, pos = r & 31;
    const int cell = b * NCELLS + pos;
    const int t = threadIdx.x, lane = t & 63, wave = t >> 6;
    __shared__ float red[4];

    float2 v = *(const float2*)&leaf_pre[(size_t)r * SZ + 2 * t];
    float sq = v.x * v.x + v.y * v.y;
    #pragma unroll
    for (int o = 32; o; o >>= 1) sq += __shfl_xor(sq, o);
    if (lane == 0) red[wave] = sq;
    __syncthreads();
    float nrm = sqrtf(red[0] + red[1] + red[2] + red[3]);
    float inv = 1.f / fmaxf(nrm, 1e-12f);
    v.x *= inv; v.y *= inv;
    f32x2 vv; vv.x = v.x; vv.y = v.y;
    __builtin_nontemporal_store(vv, (f32x2*)&chart_h[(size_t)cell * SZ + 2 * t]);
    ((u32*)Hchart)[(size_t)cell * 256 + t] = pack2(f2bf(v.x), f2bf(v.y));
    if (t == 0) Sarr[cell] = 0.f;
}

// ---------------------------------------------------------------------------
// transform_mfma: ACU[cell][0:1536] (bf16) = h[cell] @ Wcat [+ b_comp on A].
// 64x64 tile, 4 waves (2x2), wave 32x32, BK=32. ROW-chunk XCD pinning.
// ---------------------------------------------------------------------------
__global__ __launch_bounds__(256) void transform_mfma(
    const u16* __restrict__ Hchart, const u16* __restrict__ WT,
    const float* __restrict__ b_comp,
    u16* __restrict__ ACU, int level, int nrt)
{
    __shared__ u16 Ah[64][40];
    __shared__ u16 Bh[64][40];
    __shared__ int cidx[64];

    const int L = TT - level, rows = BB * L, off = off_of(level);
    const int id = blockIdx.x;
    const int w = (id & 7) * (3 * nrt) + (id >> 3);   // T/8 = 3*nrt
    const int rt = w / 24, ct = w % 24;
    const int col0 = ct * 64;

    const int t = threadIdx.x;
    if (t < 64) {
        int g = rt * 64 + t;
        cidx[t] = (g < rows) ? ((g / L) * NCELLS + off + (g % L)) : -1;
    }

    const int srow = t >> 2, skc = (t & 3) * 8;
    int ga = rt * 64 + srow;
    if (ga >= rows) ga = rows - 1;          // clamp: safe read, store guarded
    const int acell = (ga / L) * NCELLS + off + (ga % L);
    const u16* aph = Hchart + (size_t)acell * SZ + skc;
    const u16* bph = WT + (size_t)(col0 + srow) * SZ + skc;

    const int lane = t & 63, wv = t >> 6;
    const int wr = wv >> 1, wc = wv & 1;
    const int l15 = lane & 15, lko = (lane >> 4) * 8;

    f32x4 acc[2][2];
    #pragma unroll
    for (int i = 0; i < 2; ++i)
        #pragma unroll
        for (int j = 0; j < 2; ++j)
            #pragma unroll
            for (int e = 0; e < 4; ++e) acc[i][j][e] = 0.f;

    uint4 pah = *(const uint4*)aph;
    uint4 pbh = *(const uint4*)bph;

    for (int k0 = 0; k0 < SZ; k0 += 32) {
        *(uint4*)&Ah[srow][skc] = pah;
        *(uint4*)&Bh[srow][skc] = pbh;
        __syncthreads();

        if (k0 + 32 < SZ) {
            pah = *(const uint4*)(aph + k0 + 32);
            pbh = *(const uint4*)(bph + k0 + 32);
        }

        bf16x8 fah[2], fbh[2];
        #pragma unroll
        for (int i = 0; i < 2; ++i)
            fah[i] = *(const bf16x8*)&Ah[wr * 32 + i * 16 + l15][lko];
        #pragma unroll
        for (int j = 0; j < 2; ++j)
            fbh[j] = *(const bf16x8*)&Bh[wc * 32 + j * 16 + l15][lko];
        #pragma unroll
        for (int i = 0; i < 2; ++i)
            #pragma unroll
            for (int j = 0; j < 2; ++j)
                acc[i][j] = __builtin_amdgcn_mfma_f32_16x16x32_bf16(
                    fah[i], fbh[j], acc[i][j], 0, 0, 0);
        __syncthreads();
    }

    #pragma unroll
    for (int i = 0; i < 2; ++i) {
        int rbase = wr * 32 + i * 16 + (lane >> 4) * 4;
        #pragma unroll
        for (int j = 0; j < 2; ++j) {
            int gc = col0 + wc * 32 + j * 16 + l15;
            float bias = (gc < 512) ? b_comp[gc] : 0.f;  // fold comp bias into A
            #pragma unroll
            for (int q = 0; q < 4; ++q) {
                int ci = cidx[rbase + q];
                if (ci >= 0)
                    ACU[(size_t)ci * 1536 + gc] = f2bf(acc[i][j][q] + bias);
            }
        }
    }
}

// ---------------------------------------------------------------------------
// Combine: 512 threads (8 waves); XCD-swizzled; 2x-unrolled n-loops for MLP.
// bf16 ACU/Hchart reads; NT f32 chart writes. A carries the comp bias.
// ---------------------------------------------------------------------------
__global__ __launch_bounds__(512) void combine_kernel(
    float* __restrict__ chart_h, const u16* __restrict__ ACU,
    const u16* __restrict__ Hchart,
    float* __restrict__ Sarr, u16* __restrict__ Hchart_w, int level)
{
    const int L = TT - level, N = level;
    // XCD swizzle: grid C = 48L divisible by 8; XCD x gets b in [6x, 6x+6)
    const int cpx = (BB * L) >> 3;
    const int swz = (blockIdx.x & 7) * cpx + (blockIdx.x >> 3);
    const int b = swz / L, pos = swz % L;
    const int off = off_of(level);

    __shared__ float s_lds[32], p_lds[32], spre[32];
    __shared__ int lcell[32], rcell[32];
    __shared__ float hred[8][512];
    __shared__ float red[8];

    const int t = threadIdx.x, lane = t & 63, wv = t >> 6;

    if (t < N) {
        int lc = b * NCELLS + off_of(t) + pos;
        int rc = b * NCELLS + off_of(level - t - 1) + pos + t + 1;
        lcell[t] = lc;
        rcell[t] = rc;
        spre[t] = Sarr[lc] + Sarr[rc];
    }
    __syncthreads();

    // phase 1: s_n = u_l . h_r + s_l + s_r (2x unrolled: n, n+8)
    for (int n = wv; n < N; n += 16) {
        int n2 = n + 8;
        bool has2 = n2 < N;
        int nn = has2 ? n2 : n;
        const u16* u0  = ACU + (size_t)lcell[n] * 1536 + 1024;
        const u16* hr0 = Hchart + (size_t)rcell[n] * SZ;
        const u16* u1  = ACU + (size_t)lcell[nn] * 1536 + 1024;
        const u16* hr1 = Hchart + (size_t)rcell[nn] * SZ;
        uint4 uv0 = *(const uint4*)&u0[lane * 8];
        uint4 hv0 = *(const uint4*)&hr0[lane * 8];
        uint4 uv1 = *(const uint4*)&u1[lane * 8];
        uint4 hv1 = *(const uint4*)&hr1[lane * 8];
        const u32 ua[4] = {uv0.x, uv0.y, uv0.z, uv0.w};
        const u32 ha[4] = {hv0.x, hv0.y, hv0.z, hv0.w};
        const u32 ub[4] = {uv1.x, uv1.y, uv1.z, uv1.w};
        const u32 hb[4] = {hv1.x, hv1.y, hv1.z, hv1.w};
        float d0 = 0.f, d1 = 0.f;
        #pragma unroll
        for (int c = 0; c < 4; ++c) {
            float2 a0 = upk(ua[c]), g0 = upk(ha[c]);
            float2 a1 = upk(ub[c]), g1 = upk(hb[c]);
            d0 = fmaf(a0.x, g0.x, fmaf(a0.y, g0.y, d0));
            d1 = fmaf(a1.x, g1.x, fmaf(a1.y, g1.y, d1));
        }
        #pragma unroll
        for (int o = 32; o; o >>= 1) {
            d0 += __shfl_xor(d0, o);
            d1 += __shfl_xor(d1, o);
        }
        if (lane == 0) {
            s_lds[n] = d0 + spre[n];
            if (has2) s_lds[n2] = d1 + spre[n2];
        }
    }
    __syncthreads();

    // phase 1b: softmax + sbar (wave 0)
    if (wv == 0) {
        float sv = (lane < N) ? s_lds[lane] : -INFINITY;
        float m = sv;
        #pragma unroll
        for (int o = 32; o; o >>= 1) m = fmaxf(m, __shfl_xor(m, o));
        float e = (lane < N) ? expf(sv - m) : 0.f;
        float sum = e;
        #pragma unroll
        for (int o = 32; o; o >>= 1) sum += __shfl_xor(sum, o);
        float p = e / sum;
        if (lane < N) p_lds[lane] = p;
        float sb = (lane < N) ? sv * p : 0.f;
        #pragma unroll
        for (int o = 32; o; o >>= 1) sb += __shfl_xor(sb, o);
        if (lane == 0) Sarr[(size_t)b * NCELLS + off + pos] = sb;
    }
    __syncthreads();

    // phase 2: per-wave partial hbar (2x unrolled: n, n+8)
    float hacc[8];
    #pragma unroll
    for (int q = 0; q < 8; ++q) hacc[q] = 0.f;
    for (int n = wv; n < N; n += 16) {
        int n2 = n + 8;
        bool has2 = n2 < N;
        int nn = has2 ? n2 : n;
        const u16* A0 = ACU + (size_t)lcell[n] * 1536;
        const u16* C0 = ACU + (size_t)rcell[n] * 1536 + 512;
        const u16* A1 = ACU + (size_t)lcell[nn] * 1536;
        const u16* C1 = ACU + (size_t)rcell[nn] * 1536 + 512;
        uint4 va0 = *(const uint4*)&A0[lane * 8];
        uint4 vc0 = *(const uint4*)&C0[lane * 8];
        uint4 va1 = *(const uint4*)&A1[lane * 8];
        uint4 vc1 = *(const uint4*)&C1[lane * 8];
        float p0 = p_lds[n];
        float p1 = has2 ? p_lds[n2] : 0.f;   // values finite -> 0*x = 0
        const u32 aa[4] = {va0.x, va0.y, va0.z, va0.w};
        const u32 ca[4] = {vc0.x, vc0.y, vc0.z, vc0.w};
        const u32 ab[4] = {va1.x, va1.y, va1.z, va1.w};
        const u32 cb[4] = {vc1.x, vc1.y, vc1.z, vc1.w};
        #pragma unroll
        for (int c = 0; c < 4; ++c) {
            float2 x0 = upk(aa[c]), y0 = upk(ca[c]);
            float2 x1 = upk(ab[c]), y1 = upk(cb[c]);
            hacc[c * 2]     = fmaf(p0, fmaxf(x0.x + y0.x, 0.f), hacc[c * 2]);
            hacc[c * 2 + 1] = fmaf(p0, fmaxf(x0.y + y0.y, 0.f), hacc[c * 2 + 1]);
            hacc[c * 2]     = fmaf(p1, fmaxf(x1.x + y1.x, 0.f), hacc[c * 2]);
            hacc[c * 2 + 1] = fmaf(p1, fmaxf(x1.y + y1.y, 0.f), hacc[c * 2 + 1]);
        }
    }
    *(float4*)&hred[wv][lane * 8]     = *(float4*)&hacc[0];
    *(float4*)&hred[wv][lane * 8 + 4] = *(float4*)&hacc[4];
    __syncthreads();

    // final: thread t owns output t (512 threads)
    float hv = hred[0][t] + hred[1][t] + hred[2][t] + hred[3][t]
             + hred[4][t] + hred[5][t] + hred[6][t] + hred[7][t];

    float sq = hv * hv;
    #pragma unroll
    for (int o = 32; o; o >>= 1) sq += __shfl_xor(sq, o);
    if (lane == 0) red[wv] = sq;
    __syncthreads();
    float nrm = sqrtf(((red[0] + red[1]) + (red[2] + red[3]))
                    + ((red[4] + red[5]) + (red[6] + red[7])));
    float inv = 1.f / fmaxf(nrm, 1e-12f);
    hv *= inv;
    hred[0][t] = hv;
    __syncthreads();
    const int ocell = b * NCELLS + off + pos;
    if (t < 256) {
        float x0 = hred[0][2 * t], x1 = hred[0][2 * t + 1];
        f32x2 vv; vv.x = x0; vv.y = x1;
        __builtin_nontemporal_store(vv,
            (f32x2*)&chart_h[(size_t)ocell * SZ + 2 * t]);
        ((u32*)Hchart_w)[(size_t)ocell * 256 + t] = pack2(f2bf(x0), f2bf(x1));
    }
}

// ---------------------------------------------------------------------------
extern "C" void kernel_launch(void* const* d_in, const int* in_sizes, int n_in,
                              void* d_out, int out_size, void* d_ws, size_t ws_size,
                              hipStream_t stream)
{
    const float* x      = (const float*)d_in[0];
    const float* w_leaf = (const float*)d_in[1];
    const float* b_leaf = (const float*)d_in[2];
    const float* w_comp = (const float*)d_in[3];
    const float* b_comp = (const float*)d_in[4];
    const float* s_bil  = (const float*)d_in[5];
    float* chart_h = (float*)d_out;

    char* ws = (char*)d_ws;
    u16* ACU    = (u16*)ws;                        ws += (size_t)BB * NCELLS * 1536 * 2;
    u16* Hchart = (u16*)ws;                        ws += (size_t)BB * NCELLS * SZ * 2;
    float* Sarr = (float*)ws;                      ws += (size_t)BB * NCELLS * 4;
    u16* WT     = (u16*)ws;                        ws += (size_t)1536 * SZ * 2;
    u16* WLT_hi = (u16*)ws;                        ws += (size_t)SZ * DD * 2;
    u16* WLT_lo = (u16*)ws;                        ws += (size_t)SZ * DD * 2;
    float* leaf_pre = (float*)ws;                  ws += (size_t)BB * TT * SZ * 4;

    prep_all<<<(1536 * 512 + 512 * 1024) / 256, 256, 0, stream>>>(
        w_comp, s_bil, w_leaf, WT, WLT_hi, WLT_lo);
    leaf_mfma<<<dim3(8, 12), 256, 0, stream>>>(x, WLT_hi, WLT_lo, b_leaf, leaf_pre);
    leaf_norm<<<BB * TT, 256, 0, stream>>>(leaf_pre, chart_h, Hchart, Sarr);

    {
        int nrt = (BB * TT + 63) / 64;   // 24
        transform_mfma<<<24 * nrt, 256, 0, stream>>>(
            Hchart, WT, b_comp, ACU, 0, nrt);
    }

    for (int level = 1; level < TT; ++level) {
        int L = TT - level;
        combine_kernel<<<BB * L, 512, 0, stream>>>(
            chart_h, ACU, Hchart, Sarr, Hchart, level);
        if (level < TT - 1) {
            int nrt = (BB * L + 63) / 64;
            transform_mfma<<<24 * nrt, 256, 0, stream>>>(
                Hchart, WT, b_comp, ACU, level, nrt);
        }
    }
}